// Round 2
// baseline (138.842 us; speedup 1.0000x reference)
//
#include <hip/hip_runtime.h>
#include <hip/hip_bf16.h>

typedef __bf16 bf16_t;
typedef __bf16 bf16x4 __attribute__((ext_vector_type(4)));
typedef __bf16 bf16x8 __attribute__((ext_vector_type(8)));
typedef float f32x4 __attribute__((ext_vector_type(4)));

#define B_ 2
#define T_ 2048
#define C_ 1024
#define H_ 16
#define HD_ 64
#define RD_ 32
#define M_ (B_ * T_)  // 4096

// ---------------- convert x fp32 -> bf16 ----------------
__global__ __launch_bounds__(256) void k_cvt(const float* __restrict__ in,
                                             bf16_t* __restrict__ out, int n4) {
    int i = blockIdx.x * 256 + threadIdx.x;
    if (i >= n4) return;
    float4 v = reinterpret_cast<const float4*>(in)[i];
    bf16x4 o;
    o[0] = (bf16_t)v.x; o[1] = (bf16_t)v.y; o[2] = (bf16_t)v.z; o[3] = (bf16_t)v.w;
    reinterpret_cast<bf16x4*>(out)[i] = o;
}

// ---------------- transpose + convert W (NxN fp32 -> Wt[n][k] bf16) ----------------
__global__ __launch_bounds__(256) void k_transpose_cvt(const float* __restrict__ W,
                                                       bf16_t* __restrict__ Wt, int N) {
    __shared__ float tile[32][33];
    int n0 = blockIdx.x * 32, k0 = blockIdx.y * 32;
    int tx = threadIdx.x, ty = threadIdx.y;
    for (int i = ty; i < 32; i += 8)
        tile[i][tx] = W[(size_t)(k0 + i) * N + n0 + tx];
    __syncthreads();
    for (int i = ty; i < 32; i += 8)
        Wt[(size_t)(n0 + i) * N + k0 + tx] = (bf16_t)tile[tx][i];
}

// ---------------- GEMM: C[M][N] fp32 = A[M][K]bf16 * Bt[N][K]bf16^T ----------------
// 128x64 tile, BK=32, 4 waves (2x2, each 64x32), global_load_lds width 16.
// Grid (N/64, M/128) = 512 blocks -> 2 blocks/CU -> 8 waves/CU.
__global__ __launch_bounds__(256) void k_gemm_bt(const bf16_t* __restrict__ A,
                                                 const bf16_t* __restrict__ Bt,
                                                 float* __restrict__ C,
                                                 int M, int N, int K) {
    __shared__ bf16_t As[128 * 32];
    __shared__ bf16_t Bs[64 * 32];
    const int tid = threadIdx.x;
    const int lane = tid & 63, w = tid >> 6;
    const int wr = w >> 1, wc = w & 1;
    const int g = lane >> 4, li = lane & 15;
    const size_t rowA0 = (size_t)blockIdx.y * 128;
    const size_t colB0 = (size_t)blockIdx.x * 64;
    const bf16_t* Ab = A + rowA0 * K;
    const bf16_t* Bb = Bt + colB0 * K;
    f32x4 acc[4][2] = {};
    const int lrow = lane >> 2;       // 0..15 within a 16-row wave chunk
    const int lc8 = (lane & 3) * 8;   // element offset (16B chunks)

    for (int k0 = 0; k0 < K; k0 += 32) {
        __syncthreads();  // prior-iter LDS reads done before overwrite
#pragma unroll
        for (int half = 0; half < 2; ++half) {
            const int rbase = half * 64 + w * 16;
            const bf16_t* srcA = Ab + (size_t)(rbase + lrow) * K + k0 + lc8;
            __builtin_amdgcn_global_load_lds(
                (const __attribute__((address_space(1))) void*)srcA,
                (__attribute__((address_space(3))) void*)(As + rbase * 32), 16, 0, 0);
        }
        {
            const int rbase = w * 16;
            const bf16_t* srcB = Bb + (size_t)(rbase + lrow) * K + k0 + lc8;
            __builtin_amdgcn_global_load_lds(
                (const __attribute__((address_space(1))) void*)srcB,
                (__attribute__((address_space(3))) void*)(Bs + rbase * 32), 16, 0, 0);
        }
        __syncthreads();  // drains vmcnt: staged data visible
        bf16x8 af[4], bfv[2];
#pragma unroll
        for (int i = 0; i < 4; ++i)
            af[i]  = *reinterpret_cast<const bf16x8*>(As + (wr * 64 + i * 16 + li) * 32 + g * 8);
#pragma unroll
        for (int j = 0; j < 2; ++j)
            bfv[j] = *reinterpret_cast<const bf16x8*>(Bs + (wc * 32 + j * 16 + li) * 32 + g * 8);
#pragma unroll
        for (int i = 0; i < 4; ++i)
#pragma unroll
            for (int j = 0; j < 2; ++j)
                acc[i][j] = __builtin_amdgcn_mfma_f32_16x16x32_bf16(af[i], bfv[j], acc[i][j], 0, 0, 0);
    }
#pragma unroll
    for (int i = 0; i < 4; ++i)
#pragma unroll
        for (int j = 0; j < 2; ++j)
#pragma unroll
            for (int r = 0; r < 4; ++r) {
                size_t row = rowA0 + wr * 64 + i * 16 + g * 4 + r;
                size_t col = colB0 + wc * 32 + j * 16 + li;
                C[row * N + col] = acc[i][j][r];
            }
}

// ---------------- fused RoPE + RMS-norm; writes q (B,H,T,64) AND qT (B,H,64,T) ----------------
// grid (T/64, H, B), 256 threads. Thread: t = t0 + (tid>>2), d-quarter = tid&3.
__global__ __launch_bounds__(256) void k_rope_rms(const float* __restrict__ w32,
                                                  const float* __restrict__ ct,
                                                  const float* __restrict__ st,
                                                  bf16_t* __restrict__ q,
                                                  bf16_t* __restrict__ qT) {
    __shared__ bf16_t tile[64][72];
    const int tid = threadIdx.x;
    const int tl = tid >> 2;       // 0..63 local t
    const int dq = tid & 3;        // d quarter (16 elems)
    const int t0 = blockIdx.x * 64;
    const int h = blockIdx.y, b = blockIdx.z;
    const int t = t0 + tl;
    const float* src = w32 + ((size_t)b * T_ + t) * C_ + h * 64 + dq * 16;
    float v[16];
#pragma unroll
    for (int c4 = 0; c4 < 4; ++c4) {
        float4 f = reinterpret_cast<const float4*>(src)[c4];
        v[c4 * 4 + 0] = f.x; v[c4 * 4 + 1] = f.y; v[c4 * 4 + 2] = f.z; v[c4 * 4 + 3] = f.w;
    }
    // rotary partner: d +/- 32 lives in thread tid^2 (dq flips bit1)
    float p[16];
#pragma unroll
    for (int e = 0; e < 16; ++e) p[e] = __shfl_xor(v[e], 2);
    const float* cp = ct + (size_t)t * RD_ + (dq & 1) * 16;
    const float* sp = st + (size_t)t * RD_ + (dq & 1) * 16;
    float y[16];
    float sq = 0.f;
#pragma unroll
    for (int e = 0; e < 16; ++e) {
        float c = cp[e], s = sp[e];
        float yy = (dq < 2) ? (v[e] * c + p[e] * s) : (v[e] * c - p[e] * s);
        y[e] = yy;
        sq += yy * yy;
    }
    sq += __shfl_xor(sq, 1);
    sq += __shfl_xor(sq, 2);
    float rn = rsqrtf(sq * (1.0f / 64.0f) + 1.1920929e-7f);
    bf16x8 lo, hi;
#pragma unroll
    for (int e = 0; e < 8; ++e) { lo[e] = (bf16_t)(y[e] * rn); hi[e] = (bf16_t)(y[e + 8] * rn); }
    bf16_t* qrow = q + (((size_t)(b * H_ + h) * T_) + t) * 64 + dq * 16;
    *reinterpret_cast<bf16x8*>(qrow) = lo;
    *reinterpret_cast<bf16x8*>(qrow + 8) = hi;
    *reinterpret_cast<bf16x8*>(&tile[tl][dq * 16]) = lo;
    *reinterpret_cast<bf16x8*>(&tile[tl][dq * 16 + 8]) = hi;
    __syncthreads();
    // transposed write: thread: d-row = tid>>2, t-chunk = (tid&3)*16
    const int dl = tid >> 2, tq = tid & 3;
    bf16x8 zlo, zhi;
#pragma unroll
    for (int e = 0; e < 8; ++e) { zlo[e] = tile[tq * 16 + e][dl]; zhi[e] = tile[tq * 16 + 8 + e][dl]; }
    bf16_t* dst = qT + ((size_t)(b * H_ + h) * 64 + dl) * T_ + t0 + tq * 16;
    *reinterpret_cast<bf16x8*>(dst) = zlo;
    *reinterpret_cast<bf16x8*>(dst + 8) = zhi;
}

// ---------------- flash attention, sliding window; barrier-free ----------------
// grid (T/64, H, B), 256 threads; wave w handles queries qw..qw+15.
// QK^T computed swapped: mfma(K,Q) -> S^T, col=lane&15=query -> softmax is
// 15 in-reg fmax + 2 shfl_xor; P is row-per-query -> vectorized pb write.
// K,Q read from q (B,H,T,64); V^T read from qT (B,H,64,T). No __syncthreads.
__global__ __launch_bounds__(256, 4) void k_attn(const bf16_t* __restrict__ q,
                                                 const bf16_t* __restrict__ qT,
                                                 bf16_t* __restrict__ aout,
                                                 const int* __restrict__ wlp) {
    __shared__ bf16_t pb[4][16][72];   // per-wave P [q][key], 16B-aligned rows
    const int tid = threadIdx.x;
    const int lane = tid & 63, w = tid >> 6;
    const int g = lane >> 4, li = lane & 15;
    const int Q0 = blockIdx.x * 64;
    const int h = blockIdx.y, b = blockIdx.z;
    const bf16_t* base  = q  + ((size_t)(b * H_ + h) * T_) * 64;
    const bf16_t* baseT = qT + ((size_t)(b * H_ + h) * 64) * T_;
    const int wl = wlp[0];
    const int wle = (wl <= 0 || wl > T_) ? T_ : wl;
    const int qw = Q0 + w * 16;
    const int qg = qw + li;            // this lane's query (softmax phase)

    bf16x8 aq[2];
    aq[0] = *reinterpret_cast<const bf16x8*>(base + (size_t)(qw + li) * 64 + g * 8);
    aq[1] = *reinterpret_cast<const bf16x8*>(base + (size_t)(qw + li) * 64 + 32 + g * 8);

    f32x4 o[4] = {};
    float m = -1e30f, l = 0.f;

    const int lowj = qw - wle;
    const int kb0 = (lowj > 0) ? (lowj >> 6) : 0;
    const int kb1 = qw >> 6;

    for (int kb = kb0; kb <= kb1; ++kb) {
        const int J0 = kb << 6;
        f32x4 s4[4] = {};
#pragma unroll
        for (int ks = 0; ks < 2; ++ks)
#pragma unroll
            for (int nb = 0; nb < 4; ++nb) {
                bf16x8 kf = *reinterpret_cast<const bf16x8*>(
                    base + (size_t)(J0 + nb * 16 + li) * 64 + ks * 32 + g * 8);
                s4[nb] = __builtin_amdgcn_mfma_f32_16x16x32_bf16(kf, aq[ks], s4[nb], 0, 0, 0);
            }
        // mask + online softmax; lane owns query qg, keys J0+nb*16+g*4+r
        float sv[4][4];
        float mn = m;
#pragma unroll
        for (int nb = 0; nb < 4; ++nb)
#pragma unroll
            for (int r = 0; r < 4; ++r) {
                const int j = J0 + nb * 16 + g * 4 + r;
                const int dist = qg - j;
                float x = s4[nb][r] * 0.125f;  // HD^-0.5
                sv[nb][r] = (dist >= 0 && dist <= wle) ? x : -__builtin_inff();
                mn = fmaxf(mn, sv[nb][r]);
            }
        mn = fmaxf(mn, __shfl_xor(mn, 16));
        mn = fmaxf(mn, __shfl_xor(mn, 32));
        const float al = __expf(m - mn);
        m = mn;
        float la = 0.f;
#pragma unroll
        for (int nb = 0; nb < 4; ++nb)
#pragma unroll
            for (int r = 0; r < 4; ++r) {
                float pv = __expf(sv[nb][r] - m);
                sv[nb][r] = pv;
                la += pv;
            }
        la += __shfl_xor(la, 16);
        la += __shfl_xor(la, 32);
        l = l * al + la;
        // P -> LDS (vectorized 8B stores, contiguous keys)
#pragma unroll
        for (int nb = 0; nb < 4; ++nb) {
            bf16x4 pk;
            pk[0] = (bf16_t)sv[nb][0]; pk[1] = (bf16_t)sv[nb][1];
            pk[2] = (bf16_t)sv[nb][2]; pk[3] = (bf16_t)sv[nb][3];
            *reinterpret_cast<bf16x4*>(&pb[w][li][nb * 16 + g * 4]) = pk;
        }
        // rescale O (PV layout: row=query g*4+r) — fetch al for that query
        float alq[4];
#pragma unroll
        for (int r = 0; r < 4; ++r) alq[r] = __shfl(al, g * 4 + r);
#pragma unroll
        for (int dnb = 0; dnb < 4; ++dnb)
#pragma unroll
            for (int r = 0; r < 4; ++r) o[dnb][r] *= alq[r];
        // PV: A = P rows (from pb), B = V^T rows (from qT)
#pragma unroll
        for (int ks = 0; ks < 2; ++ks) {
            bf16x8 pa = *reinterpret_cast<const bf16x8*>(&pb[w][li][ks * 32 + g * 8]);
#pragma unroll
            for (int dnb = 0; dnb < 4; ++dnb) {
                bf16x8 vf = *reinterpret_cast<const bf16x8*>(
                    baseT + (size_t)(dnb * 16 + li) * T_ + J0 + ks * 32 + g * 8);
                o[dnb] = __builtin_amdgcn_mfma_f32_16x16x32_bf16(pa, vf, o[dnb], 0, 0, 0);
            }
        }
    }
    const float rli = 1.0f / l;
    float rlq[4];
#pragma unroll
    for (int r = 0; r < 4; ++r) rlq[r] = __shfl(rli, g * 4 + r);
#pragma unroll
    for (int dnb = 0; dnb < 4; ++dnb)
#pragma unroll
        for (int r = 0; r < 4; ++r) {
            size_t t = (size_t)qw + g * 4 + r;
            aout[((size_t)b * T_ + t) * C_ + h * 64 + dnb * 16 + li] =
                (bf16_t)(o[dnb][r] * rlq[r]);
        }
}

extern "C" void kernel_launch(void* const* d_in, const int* in_sizes, int n_in,
                              void* d_out, int out_size, void* d_ws, size_t ws_size,
                              hipStream_t stream) {
    const float* x     = (const float*)d_in[0];
    const float* ct    = (const float*)d_in[1];
    const float* st    = (const float*)d_in[2];
    const float* Wqkv  = (const float*)d_in[3];
    const float* Wproj = (const float*)d_in[4];
    const int*   wl    = (const int*)d_in[5];
    float* out = (float*)d_out;
    char* ws = (char*)d_ws;

    bf16_t* xb    = (bf16_t*)(ws);                       // 8 MB  x in bf16
    bf16_t* wqkvt = (bf16_t*)(ws + (8ull << 20));        // 2 MB  W_qkv^T bf16
    bf16_t* wprot = (bf16_t*)(ws + (10ull << 20));       // 2 MB  W_proj^T bf16
    float*  w32   = (float*) (ws + (12ull << 20));       // 16 MB qkv GEMM out fp32
    bf16_t* q     = (bf16_t*)(ws + (28ull << 20));       // 8 MB  (B,H,T,64)
    bf16_t* qT    = (bf16_t*)(ws + (36ull << 20));       // 8 MB  (B,H,64,T)
    bf16_t* ao    = (bf16_t*)(ws + (12ull << 20));       // reuse w32 region (dead after rope)

    k_cvt<<<dim3((M_ * C_ / 4 + 255) / 256), dim3(256), 0, stream>>>(x, xb, M_ * C_ / 4);
    k_transpose_cvt<<<dim3(32, 32), dim3(32, 8), 0, stream>>>(Wqkv, wqkvt, C_);
    k_transpose_cvt<<<dim3(32, 32), dim3(32, 8), 0, stream>>>(Wproj, wprot, C_);
    k_gemm_bt<<<dim3(C_ / 64, M_ / 128), dim3(256), 0, stream>>>(xb, wqkvt, w32, M_, C_, C_);
    k_rope_rms<<<dim3(T_ / 64, H_, B_), dim3(256), 0, stream>>>(w32, ct, st, q, qT);
    k_attn<<<dim3(T_ / 64, H_, B_), dim3(256), 0, stream>>>(q, qT, ao, wl);
    k_gemm_bt<<<dim3(C_ / 64, M_ / 128), dim3(256), 0, stream>>>(ao, wprot, out, M_, C_, C_);
}